// Round 1
// baseline (306.791 us; speedup 1.0000x reference)
//
#include <hip/hip_runtime.h>

// Walsh-Hadamard, N = 2^25 fp32. Two passes (stages commute):
//   pass1: bits 0..13 within contiguous 2^14 tiles
//   pass2: bits 14..24 = column transform of a (2048 x 2^14) matrix view
// Both passes: register butterflies + bank-swizzled b128 LDS exchanges.

__device__ __forceinline__ void bfly(float4& a, float4& b) {
  float ax = a.x, ay = a.y, az = a.z, aw = a.w;
  a.x = ax + b.x; a.y = ay + b.y; a.z = az + b.z; a.w = aw + b.w;
  b.x = ax - b.x; b.y = ay - b.y; b.z = az - b.z; b.w = aw - b.w;
}

// 4 butterfly stages across the 4 index bits of v[16]
__device__ __forceinline__ void cross4(float4 (&v)[16]) {
#pragma unroll
  for (int m = 0; m < 4; ++m) {
#pragma unroll
    for (int k = 0; k < 16; ++k) {
      if (!(k & (1 << m))) bfly(v[k], v[k | (1 << m)]);
    }
  }
}

// ---------------- pass 1: bits 0..13 ----------------
// tile = 2^14 floats, 256 threads, 16 float4/thread, 64 KiB LDS.
// LDS float4-index swizzle: L(q) = q ^ ((q>>4)&15) -> conflict-free for all
// three access patterns (verified per 8-lane group).
__global__ __launch_bounds__(256) void wht_pass1(const float4* __restrict__ in4,
                                                 float4* __restrict__ out4) {
  __shared__ float4 lds[4096];  // 64 KiB
  const int t = threadIdx.x;
  const int base4 = (int)blockIdx.x << 12;  // tile base in float4s
  float4 v[16];
#pragma unroll
  for (int k = 0; k < 16; ++k) v[k] = in4[base4 + t + (k << 8)];
  // bits 0 and 1 (inside each float4)
#pragma unroll
  for (int k = 0; k < 16; ++k) {
    float4 a = v[k];
    float s0 = a.x + a.y, d0 = a.x - a.y, s1 = a.z + a.w, d1 = a.z - a.w;
    v[k].x = s0 + s1; v[k].y = d0 + d1; v[k].z = s0 - s1; v[k].w = d0 - d1;
  }
  cross4(v);  // bits 10..13 (k = e[13:10])

  // exchange 1: -> thread holds u = e[5:2]
#pragma unroll
  for (int k = 0; k < 16; ++k) { int q = t + (k << 8); lds[q ^ ((q >> 4) & 15)] = v[k]; }
  __syncthreads();
#pragma unroll
  for (int u = 0; u < 16; ++u) { int q = u + (t << 4); v[u] = lds[q ^ ((q >> 4) & 15)]; }
  cross4(v);  // bits 2..5

  // exchange 2: write set == own read set -> no barrier needed before writes
#pragma unroll
  for (int u = 0; u < 16; ++u) { int q = u + (t << 4); lds[q ^ ((q >> 4) & 15)] = v[u]; }
  __syncthreads();
  const int c0 = t & 15, c1 = t >> 4;
#pragma unroll
  for (int u = 0; u < 16; ++u) {
    int q = c0 + (u << 4) + (c1 << 8);
    v[u] = lds[q ^ ((q >> 4) & 15)];
  }
  cross4(v);  // bits 6..9 (u = e[9:6])

#pragma unroll
  for (int u = 0; u < 16; ++u) out4[base4 + c0 + (u << 4) + (c1 << 8)] = v[u];
}

// ---------------- pass 2: bits 14..24 ----------------
// rows r = idx>>14 (2048), cols = idx & 0x3fff. Tile = all rows x 32 cols.
// 1024 threads, 16 float4/thread. LDS = one column-quarter (2048 rows x 8
// cols = 64 KiB); exchanges run in 4 quarter-rounds gated by qt = (t>>1)&3.
// Quarter LDS index q = 2*r + (c4&1); swizzle L(q) = q ^ (((q>>8)&3)<<1).
__global__ __launch_bounds__(1024, 4) void wht_pass2(float4* __restrict__ b4) {
  __shared__ float4 lds[4096];  // 64 KiB
  const int t = threadIdx.x;
  const int cb4 = (int)blockIdx.x << 3;  // column base in float4s (32 cols)
  const int c4 = t & 7;                  // which float4 within 32-col segment
  const int cc = t & 1;                  // c4 bit 0
  const int qt = (t >> 1) & 3;           // c4 bits 1..2 = quarter id
  const int rlo = t >> 3;                // row bits 0..6 (load layout)
  float4 v[16];
#pragma unroll
  for (int k = 0; k < 16; ++k)
    v[k] = b4[((long)(rlo + (k << 7)) << 12) + cb4 + c4];
  cross4(v);  // row bits 7..10 (k)

  // exchange 1: A(rlo, k) -> B(rb = r[3:0] in regs, rhi = t>>3)
#pragma unroll 1
  for (int r4 = 0; r4 < 4; ++r4) {
    __syncthreads();
    if (qt == r4) {
#pragma unroll
      for (int k = 0; k < 16; ++k) {
        int q = ((rlo + (k << 7)) << 1) | cc;
        lds[q ^ (((q >> 8) & 3) << 1)] = v[k];
      }
    }
    __syncthreads();
    if (qt == r4) {
#pragma unroll
      for (int rb = 0; rb < 16; ++rb) {
        int q = ((rb + (rlo << 4)) << 1) | cc;
        v[rb] = lds[q ^ (((q >> 8) & 3) << 1)];
      }
    }
  }
  cross4(v);  // row bits 0..3 (rb)

  // exchange 2: B -> C. C-thread: rlowC = r[3:0], rhi4C = r[10:7],
  // holds rm = r[6:4] (8) x c (2 adjacent float4-cols in own quarter).
  const int rlowC = (t >> 3) & 15;
  const int rhi4C = (t & 1) | (((t >> 7) & 7) << 1);
#pragma unroll 1
  for (int r4 = 0; r4 < 4; ++r4) {
    __syncthreads();
    if (qt == r4) {  // B-write: same addresses this thread read in exchange 1
#pragma unroll
      for (int rb = 0; rb < 16; ++rb) {
        int q = ((rb + (rlo << 4)) << 1) | cc;
        lds[q ^ (((q >> 8) & 3) << 1)] = v[rb];
      }
    }
    __syncthreads();
    if (qt == r4) {
#pragma unroll
      for (int i = 0; i < 16; ++i) {
        int rm = i & 7, c = i >> 3;
        int r = rlowC + (rm << 4) + (rhi4C << 7);
        int q = (r << 1) | c;
        v[i] = lds[q ^ (((q >> 8) & 3) << 1)];
      }
    }
  }
  // row bits 4..6 (rm = low 3 bits of i; bit 3 of i is the column, untouched)
#pragma unroll
  for (int m = 0; m < 3; ++m) {
#pragma unroll
    for (int i = 0; i < 16; ++i) {
      if (!(i & (1 << m))) bfly(v[i], v[i | (1 << m)]);
    }
  }

#pragma unroll
  for (int i = 0; i < 16; ++i) {
    int rm = i & 7, c = i >> 3;
    int r = rlowC + (rm << 4) + (rhi4C << 7);
    b4[((long)r << 12) + cb4 + (qt << 1) + c] = v[i];
  }
}

extern "C" void kernel_launch(void* const* d_in, const int* in_sizes, int n_in,
                              void* d_out, int out_size, void* d_ws, size_t ws_size,
                              hipStream_t stream) {
  (void)in_sizes; (void)n_in; (void)d_ws; (void)ws_size; (void)out_size;
  const float* x = (const float*)d_in[0];
  float* out = (float*)d_out;
  // pass1: 2^25 / 2^14 = 2048 tiles
  wht_pass1<<<2048, 256, 0, stream>>>((const float4*)x, (float4*)out);
  // pass2: 2^14 cols / 32 = 512 tiles, in-place on d_out
  wht_pass2<<<512, 1024, 0, stream>>>((float4*)out);
}